// Round 2
// baseline (252.426 us; speedup 1.0000x reference)
//
#include <hip/hip_runtime.h>

#define MROWS 16384
#define KD 2048
#define NQ 256
#define NE 64
#define INV_SQRT_DQ 0.0625f
#define NOISE_STD_C 0.1f

typedef _Float16 f16x8 __attribute__((ext_vector_type(8)));
typedef float f32x4 __attribute__((ext_vector_type(4)));

__device__ inline void split8v(f32x4 a, f32x4 b, f16x8* h, f16x8* l) {
    f16x8 hh, ll;
#pragma unroll
    for (int i = 0; i < 4; ++i) {
        _Float16 s = (_Float16)a[i];
        hh[i] = s; ll[i] = (_Float16)(a[i] - (float)s);
    }
#pragma unroll
    for (int i = 0; i < 4; ++i) {
        _Float16 s = (_Float16)b[i];
        hh[4 + i] = s; ll[4 + i] = (_Float16)(b[i] - (float)s);
    }
    *h = hh; *l = ll;
}

// ---------------------------------------------------------------------------
// Kernel 1: fold W2 = w_q @ keys.T  ([2048][64], fp64 accumulate -> fp32),
// emitted directly in B-fragment-packed hi/lo f16 (scale NOT folded: 1/16 is
// applied exactly at the epilogue; folding it here would push lo into deep
// f16 subnormals). Also css[e] = (b_q . keys[e]) * 1/16  (block 0, wave 0).
// Thread (o, e): d = o*8..o*8+7 k-octet, one expert e. 16384 threads.
// frag layout: off(d,e) = ((d>>5)*4 + (e>>4))*512 + (((d>>3)&3)*16 + (e&15))*8 + (d&7)
__global__ __launch_bounds__(256) void prep_w2(
    const float* __restrict__ w, const float* __restrict__ keys,
    const float* __restrict__ bq, _Float16* __restrict__ whp,
    _Float16* __restrict__ wlp, float* __restrict__ css) {
    const int tid = blockIdx.x * 256 + threadIdx.x;
    const int e = tid & 63;
    const int o = tid >> 6;                 // k-octet index 0..255
    const float* kp = keys + (size_t)e * NQ;
    const float* wp = w + (size_t)o * 8 * NQ;
    double acc[8];
#pragma unroll
    for (int j = 0; j < 8; ++j) acc[j] = 0.0;
    for (int q = 0; q < NQ; q += 4) {
        f32x4 kv = *(const f32x4*)(kp + q);
#pragma unroll
        for (int j = 0; j < 8; ++j) {
            f32x4 wv = *(const f32x4*)(wp + (size_t)j * NQ + q);
#pragma unroll
            for (int u = 0; u < 4; ++u)
                acc[j] += (double)wv[u] * (double)kv[u];
        }
    }
    const int kc32 = o >> 2;
    const int qqp  = o & 3;
    const size_t base = ((size_t)kc32 * 4 + (e >> 4)) * 512 + (size_t)(qqp * 16 + (e & 15)) * 8;
    f16x8 h, l;
#pragma unroll
    for (int j = 0; j < 8; ++j) {
        float v = (float)acc[j];
        _Float16 s = (_Float16)v;
        h[j] = s;
        l[j] = (_Float16)(v - (float)s);
    }
    *(f16x8*)(whp + base) = h;
    *(f16x8*)(wlp + base) = l;
    if (blockIdx.x == 0 && threadIdx.x < NE) {
        const float* kp2 = keys + (size_t)threadIdx.x * NQ;
        double s = 0.0;
        for (int q = 0; q < NQ; ++q) s += (double)bq[q] * (double)kp2[q];
        css[threadIdx.x] = (float)(s * 0.0625);
    }
}

// ---------------------------------------------------------------------------
// Kernel 2 (fused): logits = x @ W2 (3-pass f16-split MFMA, K=2048, N=64)
// * 1/16 + css + noise*0.1, then top-2 + softmax + scatter.
// BM=64, BN=64, BK=128, ping-pong LDS, depth-4 rolling B slots (static idx),
// lgkm-only barrier. grid 256, 512 threads (8 waves: 2m x 4n split).
// HBM-bound by design: streams x (134 MB) once.
__global__ __launch_bounds__(512) void gemm2_fused(
    const float* __restrict__ x, const _Float16* __restrict__ whp,
    const _Float16* __restrict__ wlp, const float* __restrict__ css,
    const float* __restrict__ noise, float* __restrict__ gate,
    float* __restrict__ idxout) {
    // LDS: ping-pong A buffers: buf b at b*32KB = {Ah 16KB, Al 16KB}.
    // Epilogue: LG f32 [64][65] (16.6KB) aliases buf0.
    __shared__ __align__(16) char smem[65536];

    const int t = threadIdx.x;
    const int lane = t & 63;
    const int wv = t >> 6;              // 0..7
    const int wn = wv & 3;              // n-tile (16 experts)
    const int wm = wv >> 2;             // 0..1, owns m-tiles {2wm, 2wm+1}
    const int m0 = blockIdx.x * 64;
    const int f = lane & 15;
    const int qq = lane >> 4;           // 0..3

    // staging: thread owns k-octet soct (8 f32) of rows {srow, srow+32}
    const int srow = t >> 4;            // 0..31
    const int soct = t & 15;            // 0..15
    const int swoff = (soct ^ (srow & 7)) * 8;     // f16 units (XOR swizzle)
    const f32x4* xq0 = (const f32x4*)(x + (size_t)(m0 + srow) * KD + soct * 8);
    const f32x4* xq1 = (const f32x4*)(x + (size_t)(m0 + srow + 32) * KD + soct * 8);

    // B pointers (frag-packed): frag(g, wn) at whp + (g*4 + wn)*512 + lane*8
    const _Float16* bph = whp + (size_t)wn * 512 + lane * 8;
    const _Float16* bpl = wlp + (size_t)wn * 512 + lane * 8;

    f32x4 acc[2];
    acc[0] = {0.f, 0.f, 0.f, 0.f};
    acc[1] = {0.f, 0.f, 0.f, 0.f};

    // ---- prologue: tile 0 -> buf0; preload x(tile1)
    f32x4 a0 = __builtin_nontemporal_load(xq0);
    f32x4 a1 = __builtin_nontemporal_load(xq0 + 1);
    f32x4 b0 = __builtin_nontemporal_load(xq1);
    f32x4 b1 = __builtin_nontemporal_load(xq1 + 1);
    {
        _Float16* Ah = (_Float16*)smem;
        _Float16* Al = Ah + 8192;
        f16x8 h8, l8;
        split8v(a0, a1, &h8, &l8);
        *(f16x8*)(Ah + srow * 128 + swoff) = h8;
        *(f16x8*)(Al + srow * 128 + swoff) = l8;
        split8v(b0, b1, &h8, &l8);
        *(f16x8*)(Ah + (srow + 32) * 128 + swoff) = h8;
        *(f16x8*)(Al + (srow + 32) * 128 + swoff) = l8;
    }
    a0 = __builtin_nontemporal_load(xq0 + 32);
    a1 = __builtin_nontemporal_load(xq0 + 33);
    b0 = __builtin_nontemporal_load(xq1 + 32);
    b1 = __builtin_nontemporal_load(xq1 + 33);
    __syncthreads();  // one-time full drain

    // depth-4 rolling B slots: slot s holds fragments for g with g%4 == s.
    f16x8 bhS[4], blS[4];
#pragma unroll
    for (int ks = 0; ks < 4; ++ks) {
        bhS[ks] = *(const f16x8*)(bph + (size_t)ks * 2048);
        blS[ks] = *(const f16x8*)(bpl + (size_t)ks * 2048);
    }

    // ---- K loop: 16 iterations of BK=128 (4 g-steps of K=32 each)
    for (int i = 0; i < 16; ++i) {
        _Float16* AhC = (_Float16*)smem + (i & 1) * 16384;
        _Float16* AlC = AhC + 8192;
        _Float16* AhN = (_Float16*)smem + ((i & 1) ^ 1) * 16384;
        _Float16* AlN = AhN + 8192;

        // stage tile i+1 into the other buffer (x regs loaded 2 iters ago)
        if (i < 15) {
            f16x8 h8, l8;
            split8v(a0, a1, &h8, &l8);
            *(f16x8*)(AhN + srow * 128 + swoff) = h8;
            *(f16x8*)(AlN + srow * 128 + swoff) = l8;
            split8v(b0, b1, &h8, &l8);
            *(f16x8*)(AhN + (srow + 32) * 128 + swoff) = h8;
            *(f16x8*)(AlN + (srow + 32) * 128 + swoff) = l8;
        }
        // prefetch x tile i+2 (non-temporal: keep whp/wlp resident in L2)
        if (i < 14) {
            a0 = __builtin_nontemporal_load(xq0 + (i + 2) * 32);
            a1 = __builtin_nontemporal_load(xq0 + (i + 2) * 32 + 1);
            b0 = __builtin_nontemporal_load(xq1 + (i + 2) * 32);
            b1 = __builtin_nontemporal_load(xq1 + (i + 2) * 32 + 1);
        }
        // compute: 4 g-steps; consume slot ks, then refill with g+4 (~4 steps
        // of slack over L2 latency)
#pragma unroll
        for (int ks = 0; ks < 4; ++ks) {
            f16x8 ah[2], al[2];
#pragma unroll
            for (int mt = 0; mt < 2; ++mt) {
                const int row = (wm * 2 + mt) * 16 + f;
                const int ab = row * 128 + (((ks * 4 + qq) ^ (row & 7)) * 8);
                ah[mt] = *(const f16x8*)(AhC + ab);
                al[mt] = *(const f16x8*)(AlC + ab);
            }
#pragma unroll
            for (int mt = 0; mt < 2; ++mt) {
                acc[mt] = __builtin_amdgcn_mfma_f32_16x16x32_f16(ah[mt], bhS[ks], acc[mt], 0, 0, 0);
                acc[mt] = __builtin_amdgcn_mfma_f32_16x16x32_f16(ah[mt], blS[ks], acc[mt], 0, 0, 0);
                acc[mt] = __builtin_amdgcn_mfma_f32_16x16x32_f16(al[mt], bhS[ks], acc[mt], 0, 0, 0);
            }
            int gn = i * 4 + ks + 4;
            if (gn > 63) gn = 63;  // clamped redundant loads at tail
            bhS[ks] = *(const f16x8*)(bph + (size_t)gn * 2048);
            blS[ks] = *(const f16x8*)(bpl + (size_t)gn * 2048);
        }
        // raw barrier: publish LDS writes (lgkmcnt(0)) WITHOUT draining vmcnt,
        // so B/x prefetches stay in flight across the barrier.
        asm volatile("" ::: "memory");
        __builtin_amdgcn_s_waitcnt(0xC07F);  // lgkmcnt(0) only
        __builtin_amdgcn_s_barrier();
        asm volatile("" ::: "memory");
    }

    // ---- epilogue: logits = acc*1/16 + css[e] + 0.1*noise  -> LG [64][65]
    // buf0 (LG region) last touched at i=14; barriers since then cover aliasing.
    float* LG = (float*)smem;
    const int e = wn * 16 + f;
    const float cse = css[e];
#pragma unroll
    for (int mt = 0; mt < 2; ++mt)
#pragma unroll
        for (int r = 0; r < 4; ++r) {
            int row = (wm * 2 + mt) * 16 + qq * 4 + r;
            LG[row * 65 + e] = acc[mt][r] * INV_SQRT_DQ + cse +
                               NOISE_STD_C * noise[(size_t)(m0 + row) * NE + e];
        }
    __syncthreads();

    // ---- top-2 + softmax + scatter: 8 waves x 8 rows, lane = expert
    for (int i = 0; i < 8; ++i) {
        int r = wv * 8 + i;
        float v = LG[r * 65 + lane];
        float v1 = v; int i1 = lane;
#pragma unroll
        for (int off = 32; off; off >>= 1) {
            float ov = __shfl_xor(v1, off);
            int oi = __shfl_xor(i1, off);
            if (ov > v1 || (ov == v1 && oi < i1)) { v1 = ov; i1 = oi; }
        }
        float v2 = (lane == i1) ? -1e30f : v;
        int i2 = lane;
#pragma unroll
        for (int off = 32; off; off >>= 1) {
            float ov = __shfl_xor(v2, off);
            int oi = __shfl_xor(i2, off);
            if (ov > v2 || (ov == v2 && oi < i2)) { v2 = ov; i2 = oi; }
        }
        float ex = expf(v2 - v1);           // v2 <= v1, stable
        float p1 = 1.0f / (1.0f + ex);
        float p2 = ex * p1;
        float g = (lane == i1) ? p1 : ((lane == i2) ? p2 : 0.0f);
        gate[(size_t)(m0 + r) * NE + lane] = g;
        if (lane == 0) {
            float2 ii = make_float2((float)i1, (float)i2);
            *(float2*)(idxout + (size_t)(m0 + r) * 2) = ii;
        }
    }
}

// ---------------------------------------------------------------------------
extern "C" void kernel_launch(void* const* d_in, const int* in_sizes, int n_in,
                              void* d_out, int out_size, void* d_ws, size_t ws_size,
                              hipStream_t stream) {
    const float* x     = (const float*)d_in[0];
    const float* noise = (const float*)d_in[1];
    const float* w_q   = (const float*)d_in[2];
    const float* b_q   = (const float*)d_in[3];
    const float* keys  = (const float*)d_in[4];
    float* out = (float*)d_out;

    char* ws = (char*)d_ws;
    _Float16* whp = (_Float16*)ws;                  // 256 KB, frag-packed hi
    _Float16* wlp = (_Float16*)(ws + (256u << 10)); // 256 KB, frag-packed lo
    float* css    = (float*)(ws + (512u << 10));    // 256 B

    prep_w2<<<64, 256, 0, stream>>>(w_q, keys, b_q, whp, wlp, css);
    gemm2_fused<<<256, 512, 0, stream>>>(x, whp, wlp, css, noise,
                                         out, out + (size_t)MROWS * NE);
}

// Round 3
// 236.487 us; speedup vs baseline: 1.0674x; 1.0674x over previous
//
#include <hip/hip_runtime.h>

#define MROWS 16384
#define KD 2048
#define NQ 256
#define NE 64
#define INV_SQRT_DQ 0.0625f
#define NOISE_STD_C 0.1f

typedef _Float16 f16x8 __attribute__((ext_vector_type(8)));
typedef float f32x4 __attribute__((ext_vector_type(4)));

__device__ inline void split8v(f32x4 a, f32x4 b, f16x8* h, f16x8* l) {
    f16x8 hh, ll;
#pragma unroll
    for (int i = 0; i < 4; ++i) {
        _Float16 s = (_Float16)a[i];
        hh[i] = s; ll[i] = (_Float16)(a[i] - (float)s);
    }
#pragma unroll
    for (int i = 0; i < 4; ++i) {
        _Float16 s = (_Float16)b[i];
        hh[4 + i] = s; ll[4 + i] = (_Float16)(b[i] - (float)s);
    }
    *h = hh; *l = ll;
}

// ---------------------------------------------------------------------------
// Kernel 1: W2 = w_q @ keys.T ([2048][64], fp64 accumulate -> f32), emitted
// B-fragment-packed hi/lo f16. Parallelized: 256 blocks, block o owns k-rows
// o*8..o*8+7; threads (qc,e) q-split-4, LDS combine. css[e] = (b_q.keys[e])/16
// computed by all 256 threads of block 0 (no serial loop).
// frag layout: off(d,e) = ((d>>5)*4 + (e>>4))*512 + (((d>>3)&3)*16 + (e&15))*8 + (d&7)
__global__ __launch_bounds__(256) void prep_w2(
    const float* __restrict__ w, const float* __restrict__ keys,
    const float* __restrict__ bq, _Float16* __restrict__ whp,
    _Float16* __restrict__ wlp, float* __restrict__ css) {
    __shared__ double part[4][64][8];
    const int t = threadIdx.x;
    const int e = t & 63;
    const int qc = t >> 6;                 // 0..3 q-chunk (and wave id)
    const int o = blockIdx.x;              // 0..255 k-octet
    const float* kp = keys + (size_t)e * NQ + qc * 64;
    const float* wp = w + (size_t)o * 8 * NQ + qc * 64;
    double acc[8];
#pragma unroll
    for (int j = 0; j < 8; ++j) acc[j] = 0.0;
    for (int q = 0; q < 64; q += 4) {
        f32x4 kv = *(const f32x4*)(kp + q);
#pragma unroll
        for (int j = 0; j < 8; ++j) {
            f32x4 wv = *(const f32x4*)(wp + (size_t)j * NQ + q);
#pragma unroll
            for (int u = 0; u < 4; ++u)
                acc[j] += (double)wv[u] * (double)kv[u];
        }
    }
#pragma unroll
    for (int j = 0; j < 8; ++j) part[qc][e][j] = acc[j];
    __syncthreads();
    if (t < 64) {
        const size_t base = ((size_t)(o >> 2) * 4 + (e >> 4)) * 512 +
                            (size_t)((o & 3) * 16 + (e & 15)) * 8;
        f16x8 h, l;
#pragma unroll
        for (int j = 0; j < 8; ++j) {
            float v = (float)(part[0][e][j] + part[1][e][j] +
                              part[2][e][j] + part[3][e][j]);
            _Float16 s = (_Float16)v;
            h[j] = s;
            l[j] = (_Float16)(v - (float)s);
        }
        *(f16x8*)(whp + base) = h;
        *(f16x8*)(wlp + base) = l;
    }
    if (blockIdx.x == 0) {
        __syncthreads();  // packing reads of part[] complete
        double p = 0.0;
        const float* bp2 = bq + qc * 64;
        const float* kp2 = keys + (size_t)e * NQ + qc * 64;
        for (int q = 0; q < 64; q += 4) {
            f32x4 bv = *(const f32x4*)(bp2 + q);
            f32x4 kv = *(const f32x4*)(kp2 + q);
#pragma unroll
            for (int u = 0; u < 4; ++u)
                p += (double)bv[u] * (double)kv[u];
        }
        part[qc][e][0] = p;
        __syncthreads();
        if (t < 64)
            css[e] = (float)((part[0][e][0] + part[1][e][0] +
                              part[2][e][0] + part[3][e][0]) * 0.0625);
    }
}

// ---------------------------------------------------------------------------
// Kernel 2: logits = x @ W2 (3-pass f16-split MFMA) + css + noise, top-2 +
// softmax + scatter. NO LDS in main loop, NO barriers: each wave streams its
// 16 rows HBM->reg->split->MFMA. Block = 16 rows x 4 waves (K-split-4, 512
// k each); grid 1024 x 256 -> 4096 waves (16/CU) for latency hiding.
// A-frag direct from global: lane(qq*16+f) = row f, k-octet qq. Depth-4
// rolling x prefetch, depth-2 rolling B-frag regs (L2-resident, 512KB).
__global__ __launch_bounds__(256, 2) void gemm3_fused(
    const float* __restrict__ x, const _Float16* __restrict__ whp,
    const _Float16* __restrict__ wlp, const float* __restrict__ css,
    const float* __restrict__ noise, float* __restrict__ gate,
    float* __restrict__ idxout) {
    __shared__ float comb[3 * 1040];   // waves 1..3 partial accs, lane-major
    __shared__ float LG[16 * 65];      // logits [16][65]

    const int t = threadIdx.x;
    const int lane = t & 63;
    const int wv = t >> 6;             // 0..3: K-quarter [wv*512, wv*512+512)
    const int m0 = blockIdx.x * 16;
    const int f = lane & 15;           // row within 16-row tile
    const int qq = lane >> 4;          // k-octet within 32-k step

    const float* xp = x + (size_t)(m0 + f) * KD + wv * 512 + qq * 8;
    // B frag (g,nt) at whp + (g*4+nt)*512 + lane*8 ; this wave: g = wv*16 + s
    const _Float16* bph = whp + (size_t)(wv * 16) * 2048 + lane * 8;
    const _Float16* bpl = wlp + (size_t)(wv * 16) * 2048 + lane * 8;

    f32x4 acc[4];
#pragma unroll
    for (int nt = 0; nt < 4; ++nt) acc[nt] = {0.f, 0.f, 0.f, 0.f};

    f32x4 xb[4][2];                    // x prefetch ring, depth 4 (static idx)
    f16x8 bhS[2][4], blS[2][4];        // B-frag ring, depth 2

#pragma unroll
    for (int s = 0; s < 4; ++s) {
        const f32x4* p = (const f32x4*)(xp + s * 32);
        xb[s][0] = __builtin_nontemporal_load(p);
        xb[s][1] = __builtin_nontemporal_load(p + 1);
    }
#pragma unroll
    for (int s = 0; s < 2; ++s)
#pragma unroll
        for (int nt = 0; nt < 4; ++nt) {
            bhS[s][nt] = *(const f16x8*)(bph + ((size_t)s * 4 + nt) * 512);
            blS[s][nt] = *(const f16x8*)(bpl + ((size_t)s * 4 + nt) * 512);
        }

    // 16 k-steps of 32, fully unrolled; all ring indices compile-time.
#pragma unroll
    for (int s = 0; s < 16; ++s) {
        const int js = s & 3;          // x ring slot
        const int c = s & 1;           // B ring slot
        f16x8 ah, al;
        split8v(xb[js][0], xb[js][1], &ah, &al);
#pragma unroll
        for (int nt = 0; nt < 4; ++nt) {
            acc[nt] = __builtin_amdgcn_mfma_f32_16x16x32_f16(ah, bhS[c][nt], acc[nt], 0, 0, 0);
            acc[nt] = __builtin_amdgcn_mfma_f32_16x16x32_f16(ah, blS[c][nt], acc[nt], 0, 0, 0);
            acc[nt] = __builtin_amdgcn_mfma_f32_16x16x32_f16(al, bhS[c][nt], acc[nt], 0, 0, 0);
        }
        if (s < 12) {                  // refill x slot with step s+4
            const f32x4* p = (const f32x4*)(xp + (s + 4) * 32);
            xb[js][0] = __builtin_nontemporal_load(p);
            xb[js][1] = __builtin_nontemporal_load(p + 1);
        }
        if (s < 14) {                  // refill B slot with step s+2
#pragma unroll
            for (int nt = 0; nt < 4; ++nt) {
                bhS[c][nt] = *(const f16x8*)(bph + ((size_t)(s + 2) * 4 + nt) * 512);
                blS[c][nt] = *(const f16x8*)(bpl + ((size_t)(s + 2) * 4 + nt) * 512);
            }
        }
    }

    // ---- K-split combine: waves 1..3 park partials in LDS (lane-matched,
    // conflict-free: per (nt,r) 64 consecutive floats), wave 0 accumulates.
    if (wv > 0) {
#pragma unroll
        for (int nt = 0; nt < 4; ++nt)
#pragma unroll
            for (int r = 0; r < 4; ++r)
                comb[(wv - 1) * 1040 + (nt * 4 + r) * 65 + lane] = acc[nt][r];
    }
    __syncthreads();
    if (wv == 0) {
#pragma unroll
        for (int nt = 0; nt < 4; ++nt)
#pragma unroll
            for (int r = 0; r < 4; ++r) {
                const int idx = (nt * 4 + r) * 65 + lane;
                acc[nt][r] += comb[idx];
                acc[nt][r] += comb[1040 + idx];
                acc[nt][r] += comb[2080 + idx];
            }
        // logits -> LG: acc row = qq*4+r, expert e = nt*16+f
#pragma unroll
        for (int nt = 0; nt < 4; ++nt) {
            const int e = nt * 16 + f;
            const float cs = css[e];
#pragma unroll
            for (int r = 0; r < 4; ++r) {
                const int row = qq * 4 + r;
                LG[row * 65 + e] = acc[nt][r] * INV_SQRT_DQ + cs +
                                   NOISE_STD_C * noise[(size_t)(m0 + row) * NE + e];
            }
        }
    }
    __syncthreads();

    // ---- top-2 + softmax + scatter: wave wv handles rows wv*4..wv*4+3
    for (int i = 0; i < 4; ++i) {
        const int r = wv * 4 + i;
        float v = LG[r * 65 + lane];
        float v1 = v; int i1 = lane;
#pragma unroll
        for (int off = 32; off; off >>= 1) {
            float ov = __shfl_xor(v1, off);
            int oi = __shfl_xor(i1, off);
            if (ov > v1 || (ov == v1 && oi < i1)) { v1 = ov; i1 = oi; }
        }
        float v2 = (lane == i1) ? -1e30f : v;
        int i2 = lane;
#pragma unroll
        for (int off = 32; off; off >>= 1) {
            float ov = __shfl_xor(v2, off);
            int oi = __shfl_xor(i2, off);
            if (ov > v2 || (ov == v2 && oi < i2)) { v2 = ov; i2 = oi; }
        }
        float ex = expf(v2 - v1);           // v2 <= v1, stable
        float p1 = 1.0f / (1.0f + ex);
        float p2 = ex * p1;
        float g = (lane == i1) ? p1 : ((lane == i2) ? p2 : 0.0f);
        gate[(size_t)(m0 + r) * NE + lane] = g;
        if (lane == 0) {
            float2 ii = make_float2((float)i1, (float)i2);
            *(float2*)(idxout + (size_t)(m0 + r) * 2) = ii;
        }
    }
}

// ---------------------------------------------------------------------------
extern "C" void kernel_launch(void* const* d_in, const int* in_sizes, int n_in,
                              void* d_out, int out_size, void* d_ws, size_t ws_size,
                              hipStream_t stream) {
    const float* x     = (const float*)d_in[0];
    const float* noise = (const float*)d_in[1];
    const float* w_q   = (const float*)d_in[2];
    const float* b_q   = (const float*)d_in[3];
    const float* keys  = (const float*)d_in[4];
    float* out = (float*)d_out;

    char* ws = (char*)d_ws;
    _Float16* whp = (_Float16*)ws;                  // 256 KB, frag-packed hi
    _Float16* wlp = (_Float16*)(ws + (256u << 10)); // 256 KB, frag-packed lo
    float* css    = (float*)(ws + (512u << 10));    // 256 B

    prep_w2<<<256, 256, 0, stream>>>(w_q, keys, b_q, whp, wlp, css);
    gemm3_fused<<<1024, 256, 0, stream>>>(x, whp, wlp, css, noise,
                                          out, out + (size_t)MROWS * NE);
}

// Round 4
// 228.717 us; speedup vs baseline: 1.1037x; 1.0340x over previous
//
#include <hip/hip_runtime.h>

#define MROWS 16384
#define KD 2048
#define NQ 256
#define NE 64
#define INV_SQRT_DQ 0.0625f
#define NOISE_STD_C 0.1f

typedef _Float16 f16x8 __attribute__((ext_vector_type(8)));
typedef float f32x4 __attribute__((ext_vector_type(4)));

__device__ inline void split8v(f32x4 a, f32x4 b, f16x8* h, f16x8* l) {
    f16x8 hh, ll;
#pragma unroll
    for (int i = 0; i < 4; ++i) {
        _Float16 s = (_Float16)a[i];
        hh[i] = s; ll[i] = (_Float16)(a[i] - (float)s);
    }
#pragma unroll
    for (int i = 0; i < 4; ++i) {
        _Float16 s = (_Float16)b[i];
        hh[4 + i] = s; ll[4 + i] = (_Float16)(b[i] - (float)s);
    }
    *h = hh; *l = ll;
}

// ---------------------------------------------------------------------------
// Kernel 1: W2 = w_q @ keys.T ([2048][64], fp64 accumulate -> f32), emitted
// B-fragment-packed hi/lo f16. 256 blocks, block o owns k-rows o*8..o*8+7;
// threads (qc,e) q-split-4, LDS combine. css[e] = (b_q.keys[e])/16 by block 0.
// frag layout: off(d,e) = ((d>>5)*4 + (e>>4))*512 + (((d>>3)&3)*16 + (e&15))*8 + (d&7)
__global__ __launch_bounds__(256) void prep_w2(
    const float* __restrict__ w, const float* __restrict__ keys,
    const float* __restrict__ bq, _Float16* __restrict__ whp,
    _Float16* __restrict__ wlp, float* __restrict__ css) {
    __shared__ double part[4][64][8];
    const int t = threadIdx.x;
    const int e = t & 63;
    const int qc = t >> 6;                 // 0..3 q-chunk (and wave id)
    const int o = blockIdx.x;              // 0..255 k-octet
    const float* kp = keys + (size_t)e * NQ + qc * 64;
    const float* wp = w + (size_t)o * 8 * NQ + qc * 64;
    double acc[8];
#pragma unroll
    for (int j = 0; j < 8; ++j) acc[j] = 0.0;
    for (int q = 0; q < 64; q += 4) {
        f32x4 kv = *(const f32x4*)(kp + q);
#pragma unroll
        for (int j = 0; j < 8; ++j) {
            f32x4 wv = *(const f32x4*)(wp + (size_t)j * NQ + q);
#pragma unroll
            for (int u = 0; u < 4; ++u)
                acc[j] += (double)wv[u] * (double)kv[u];
        }
    }
#pragma unroll
    for (int j = 0; j < 8; ++j) part[qc][e][j] = acc[j];
    __syncthreads();
    if (t < 64) {
        const size_t base = ((size_t)(o >> 2) * 4 + (e >> 4)) * 512 +
                            (size_t)((o & 3) * 16 + (e & 15)) * 8;
        f16x8 h, l;
#pragma unroll
        for (int j = 0; j < 8; ++j) {
            float v = (float)(part[0][e][j] + part[1][e][j] +
                              part[2][e][j] + part[3][e][j]);
            _Float16 s = (_Float16)v;
            h[j] = s;
            l[j] = (_Float16)(v - (float)s);
        }
        *(f16x8*)(whp + base) = h;
        *(f16x8*)(wlp + base) = l;
    }
    if (blockIdx.x == 0) {
        __syncthreads();  // packing reads of part[] complete
        double p = 0.0;
        const float* bp2 = bq + qc * 64;
        const float* kp2 = keys + (size_t)e * NQ + qc * 64;
        for (int q = 0; q < 64; q += 4) {
            f32x4 bv = *(const f32x4*)(bp2 + q);
            f32x4 kv = *(const f32x4*)(kp2 + q);
#pragma unroll
            for (int u = 0; u < 4; ++u)
                p += (double)bv[u] * (double)kv[u];
        }
        part[qc][e][0] = p;
        __syncthreads();
        if (t < 64)
            css[e] = (float)((part[0][e][0] + part[1][e][0] +
                              part[2][e][0] + part[3][e][0]) * 0.0625);
    }
}

// ---------------------------------------------------------------------------
// Kernel 2: logits = x @ W2 (3-pass f16-split MFMA) + css + noise, top-2 +
// softmax + scatter. Wave = 64 rows x 64 experts x 256 k (m-unroll 4 => B
// amortized 4x, x read-once). Block = 8 waves = K-chunks 0..7; partials
// combined via LDS [8][64][68], then fused epilogue. NO barriers in main
// loop; plain cached loads (no NT); distance-2 x/B prefetch suffices since
// step-slot ~480cyc at 2 waves/SIMD. grid 256 x 512 threads, 1 block/CU.
__global__ __launch_bounds__(512, 2) void gemm4_fused(
    const float* __restrict__ x, const _Float16* __restrict__ whp,
    const _Float16* __restrict__ wlp, const float* __restrict__ css,
    const float* __restrict__ noise, float* __restrict__ gate,
    float* __restrict__ idxout) {
    // part[w][row][68] f32 = 139,264 B; LG [64][68] aliases base after reduce.
    __shared__ __align__(16) char smem[139264];

    const int t = threadIdx.x;
    const int lane = t & 63;
    const int wv = t >> 6;             // 0..7: k-chunk [wv*256, wv*256+256)
    const int m0 = blockIdx.x * 64;
    const int f = lane & 15;           // row-in-tile / expert-in-tile
    const int qq = lane >> 4;          // k-octet within 32-k step

    const float* xp = x + (size_t)(m0 + f) * KD + wv * 256 + qq * 8;
    // B frag (g,nt) at whp + (g*4+nt)*512 + lane*8 ; this wave: g = wv*8 + s
    const _Float16* bph = whp + (size_t)(wv * 8) * 2048 + lane * 8;
    const _Float16* bpl = wlp + (size_t)(wv * 8) * 2048 + lane * 8;

    f32x4 acc[4][4];
#pragma unroll
    for (int mt = 0; mt < 4; ++mt)
#pragma unroll
        for (int nt = 0; nt < 4; ++nt) acc[mt][nt] = {0.f, 0.f, 0.f, 0.f};

    f32x4 xr[2][4][2];                 // x ring: [slot][mt][pair]
    f16x8 bhS[2][4], blS[2][4];        // B ring: [slot][nt]

    // prologue: groups 0,1
#pragma unroll
    for (int s = 0; s < 2; ++s) {
#pragma unroll
        for (int mt = 0; mt < 4; ++mt) {
            const f32x4* p = (const f32x4*)(xp + (size_t)mt * 16 * KD + s * 32);
            xr[s][mt][0] = p[0];
            xr[s][mt][1] = p[1];
        }
#pragma unroll
        for (int nt = 0; nt < 4; ++nt) {
            bhS[s][nt] = *(const f16x8*)(bph + (size_t)(s * 4 + nt) * 512);
            blS[s][nt] = *(const f16x8*)(bpl + (size_t)(s * 4 + nt) * 512);
        }
    }

    // 8 k-steps of 32, fully unrolled; refill distance 2, same-slot refill
    // interleaved right after consumption (WAR handled by regalloc).
#pragma unroll
    for (int s = 0; s < 8; ++s) {
        const int cs = s & 1;
#pragma unroll
        for (int mt = 0; mt < 4; ++mt) {
            f16x8 ah, al;
            split8v(xr[cs][mt][0], xr[cs][mt][1], &ah, &al);
            if (s < 6) {               // refill this mt's slot with step s+2
                const f32x4* p = (const f32x4*)(xp + (size_t)mt * 16 * KD + (s + 2) * 32);
                xr[cs][mt][0] = p[0];
                xr[cs][mt][1] = p[1];
            }
#pragma unroll
            for (int nt = 0; nt < 4; ++nt) {
                acc[mt][nt] = __builtin_amdgcn_mfma_f32_16x16x32_f16(ah, bhS[cs][nt], acc[mt][nt], 0, 0, 0);
                acc[mt][nt] = __builtin_amdgcn_mfma_f32_16x16x32_f16(ah, blS[cs][nt], acc[mt][nt], 0, 0, 0);
                acc[mt][nt] = __builtin_amdgcn_mfma_f32_16x16x32_f16(al, bhS[cs][nt], acc[mt][nt], 0, 0, 0);
            }
        }
        if (s < 6) {                   // refill B slot with step s+2 (L2/L3)
#pragma unroll
            for (int nt = 0; nt < 4; ++nt) {
                bhS[cs][nt] = *(const f16x8*)(bph + (size_t)((s + 2) * 4 + nt) * 512);
                blS[cs][nt] = *(const f16x8*)(bpl + (size_t)((s + 2) * 4 + nt) * 512);
            }
        }
    }

    // ---- park partials: part[wv][row][e], stride 68 (16B-aligned, 2-way banks)
    float* part = (float*)smem;
#pragma unroll
    for (int mt = 0; mt < 4; ++mt)
#pragma unroll
        for (int nt = 0; nt < 4; ++nt)
#pragma unroll
            for (int r = 0; r < 4; ++r)
                part[(size_t)(wv * 64 + mt * 16 + qq * 4 + r) * 68 + nt * 16 + f] =
                    acc[mt][nt][r];
    __syncthreads();

    // ---- reduce 8 k-chunks: thread t -> row t>>3, expert octet (t&7)*8
    const int rrow = t >> 3;
    const int e0 = (t & 7) * 8;
    f32x4 s0 = {0.f, 0.f, 0.f, 0.f}, s1 = {0.f, 0.f, 0.f, 0.f};
#pragma unroll
    for (int w = 0; w < 8; ++w) {
        const float* pp = part + (size_t)(w * 64 + rrow) * 68 + e0;
        f32x4 u = *(const f32x4*)pp;
        f32x4 v = *(const f32x4*)(pp + 4);
#pragma unroll
        for (int j = 0; j < 4; ++j) { s0[j] += u[j]; s1[j] += v[j]; }
    }
    // logits for this octet (regs), then publish to LG after barrier
    f32x4 c0 = *(const f32x4*)(css + e0);
    f32x4 c1 = *(const f32x4*)(css + e0 + 4);
    const float* np = noise + (size_t)(m0 + rrow) * NE + e0;
    f32x4 n0 = *(const f32x4*)np;
    f32x4 n1 = *(const f32x4*)(np + 4);
#pragma unroll
    for (int j = 0; j < 4; ++j) {
        s0[j] = s0[j] * INV_SQRT_DQ + c0[j] + NOISE_STD_C * n0[j];
        s1[j] = s1[j] * INV_SQRT_DQ + c1[j] + NOISE_STD_C * n1[j];
    }
    __syncthreads();  // all part[] reads done before LG (aliases base) write

    float* LG = (float*)smem;  // [64][68]
    *(f32x4*)(LG + (size_t)rrow * 68 + e0) = s0;
    *(f32x4*)(LG + (size_t)rrow * 68 + e0 + 4) = s1;
    __syncthreads();

    // ---- top-2 + softmax + scatter: 8 waves x 8 rows, lane = expert
    for (int i = 0; i < 8; ++i) {
        const int r = wv * 8 + i;
        float v = LG[(size_t)r * 68 + lane];
        float v1 = v; int i1 = lane;
#pragma unroll
        for (int off = 32; off; off >>= 1) {
            float ov = __shfl_xor(v1, off);
            int oi = __shfl_xor(i1, off);
            if (ov > v1 || (ov == v1 && oi < i1)) { v1 = ov; i1 = oi; }
        }
        float v2 = (lane == i1) ? -1e30f : v;
        int i2 = lane;
#pragma unroll
        for (int off = 32; off; off >>= 1) {
            float ov = __shfl_xor(v2, off);
            int oi = __shfl_xor(i2, off);
            if (ov > v2 || (ov == v2 && oi < i2)) { v2 = ov; i2 = oi; }
        }
        float ex = expf(v2 - v1);           // v2 <= v1, stable
        float p1 = 1.0f / (1.0f + ex);
        float p2 = ex * p1;
        float g = (lane == i1) ? p1 : ((lane == i2) ? p2 : 0.0f);
        gate[(size_t)(m0 + r) * NE + lane] = g;
        if (lane == 0) {
            float2 ii = make_float2((float)i1, (float)i2);
            *(float2*)(idxout + (size_t)(m0 + r) * 2) = ii;
        }
    }
}

// ---------------------------------------------------------------------------
extern "C" void kernel_launch(void* const* d_in, const int* in_sizes, int n_in,
                              void* d_out, int out_size, void* d_ws, size_t ws_size,
                              hipStream_t stream) {
    const float* x     = (const float*)d_in[0];
    const float* noise = (const float*)d_in[1];
    const float* w_q   = (const float*)d_in[2];
    const float* b_q   = (const float*)d_in[3];
    const float* keys  = (const float*)d_in[4];
    float* out = (float*)d_out;

    char* ws = (char*)d_ws;
    _Float16* whp = (_Float16*)ws;                  // 256 KB, frag-packed hi
    _Float16* wlp = (_Float16*)(ws + (256u << 10)); // 256 KB, frag-packed lo
    float* css    = (float*)(ws + (512u << 10));    // 256 B

    prep_w2<<<256, 256, 0, stream>>>(w_q, keys, b_q, whp, wlp, css);
    gemm4_fused<<<256, 512, 0, stream>>>(x, whp, wlp, css, noise,
                                         out, out + (size_t)MROWS * NE);
}